// Round 3
// baseline (268.259 us; speedup 1.0000x reference)
//
#include <hip/hip_runtime.h>
#include <math.h>

#define BB 1024
#define NN 4096
#define HH 32
#define T  512           // threads per block (8 waves), 1 block/CU (LDS-forced)
#define ITERS 64         // row-groups of 64 rows each
#define RCI 16           // iterations cached in registers (float4 c[16] = 64 VGPRs)
#define LCI 17           // iterations cached in LDS (17*512*16 B = 136 KB)
#define GRI (ITERS - RCI - LCI)   // 31 iterations re-read from global (L3-warm)

// One workgroup per batch b. ne[b] (512 KB) is read from HBM exactly once;
// 1024 rows live in VGPRs, 1088 rows in LDS, 1984 rows are re-read via L3.
__global__ __launch_bounds__(T, 2) void gnd_kernel(
    const float* __restrict__ ne,     // [B,N,H]
    const float* __restrict__ mask,   // [B,N]
    const float* __restrict__ times,  // [B]
    const float* __restrict__ W1,     // [H, 2H+1]
    const float* __restrict__ b1,     // [H]
    const float* __restrict__ Wq,     // [H,H]
    const float* __restrict__ Wk,     // [H,H]
    const int*   __restrict__ idxc,   // [B]
    float* __restrict__ out)          // [B,N]
{
    const int b   = blockIdx.x;
    const int tid = threadIdx.x;
    const int q8  = tid & 7;   // float4 chunk within a 32-float row
    const int r   = tid >> 3;  // row-in-group, 0..63

    __shared__ float s_scores[NN];            // 16 KB
    __shared__ float s_data[LCI * T * 4];     // 136 KB row cache
    __shared__ float sh_avg[HH];
    __shared__ float sh_f[HH];
    __shared__ float sh_emb[HH];
    __shared__ float sh_qk[HH];
    __shared__ float red_buf[8];

    const float* nb   = ne + (size_t)b * (NN * HH);
    const float* base = nb + r * HH + q8 * 4;   // iter i adds i*64*HH floats

    // ---------------- pass 1: one streaming read + column sums ----------------
    float4 c[RCI];
    float a0 = 0.f, a1 = 0.f, a2 = 0.f, a3 = 0.f;

    // (A) register-cached iterations: issue all 16 loads, then accumulate
    #pragma unroll
    for (int i = 0; i < RCI; ++i)
        c[i] = *reinterpret_cast<const float4*>(base + i * (64 * HH));

    // (B) LDS-cached iterations
    #pragma unroll
    for (int i = 0; i < LCI; ++i) {
        const float4 v = *reinterpret_cast<const float4*>(base + (RCI + i) * (64 * HH));
        *reinterpret_cast<float4*>(&s_data[(i * T + tid) * 4]) = v;
        a0 += v.x; a1 += v.y; a2 += v.z; a3 += v.w;
    }

    // (C) re-read-later iterations: accumulate only
    #pragma unroll
    for (int i = 0; i < GRI; ++i) {
        const float4 v = *reinterpret_cast<const float4*>(base + (RCI + LCI + i) * (64 * HH));
        a0 += v.x; a1 += v.y; a2 += v.z; a3 += v.w;
    }

    // (A') accumulate the register cache
    #pragma unroll
    for (int i = 0; i < RCI; ++i) {
        a0 += c[i].x; a1 += c[i].y; a2 += c[i].z; a3 += c[i].w;
    }

    // gather f = ne[b, idxc[b], :]
    if (tid < HH) sh_f[tid] = nb[(size_t)idxc[b] * HH + tid];

    // stage per-thread column partials (8 KB of s_scores)
    *reinterpret_cast<float4*>(&s_scores[tid * 4]) = make_float4(a0, a1, a2, a3);
    __syncthreads();

    // deterministic fixed-order column reduce
    if (tid < HH) {
        const int q = tid >> 2, j = tid & 3;
        float s = 0.f;
        #pragma unroll
        for (int rr = 0; rr < 64; ++rr) s += s_scores[(rr * 8 + q) * 4 + j];
        sh_avg[tid] = s;  // raw sum; /N applied below
    }
    __syncthreads();

    // ---------------- tiny MLP: emb -> q -> qk ----------------
    if (tid < HH) {
        const float invN = 1.0f / (float)NN;
        const float t = times[b];
        const float* w = W1 + tid * (2 * HH + 1);
        float e = b1[tid];
        #pragma unroll
        for (int j = 0; j < HH; ++j) e += (sh_avg[j] * invN) * w[j];
        #pragma unroll
        for (int j = 0; j < HH; ++j) e += sh_f[j] * w[HH + j];
        e += t * w[2 * HH];
        sh_emb[tid] = e;
    }
    __syncthreads();
    if (tid < HH) {  // q = emb @ Wq^T
        const float* w = Wq + tid * HH;
        float qv = 0.f;
        #pragma unroll
        for (int j = 0; j < HH; ++j) qv += sh_emb[j] * w[j];
        sh_f[tid] = qv;
    }
    __syncthreads();
    if (tid < HH) {  // qk[j] = sum_h q[h]*Wk[h,j], scaled 1/sqrt(H)
        float s = 0.f;
        #pragma unroll
        for (int h = 0; h < HH; ++h) s += sh_f[h] * Wk[h * HH + tid];
        sh_qk[tid] = s * 0.17677669529663687f;
    }
    __syncthreads();

    // ---------------- pass 2: scores from regs / LDS / L3 ----------------
    const float kq0 = sh_qk[q8 * 4 + 0];
    const float kq1 = sh_qk[q8 * 4 + 1];
    const float kq2 = sh_qk[q8 * 4 + 2];
    const float kq3 = sh_qk[q8 * 4 + 3];
    const float* mrow = mask + (size_t)b * NN;

    float lmax = -INFINITY;
    #pragma unroll
    for (int i = 0; i < RCI; ++i) {
        float p = c[i].x * kq0 + c[i].y * kq1 + c[i].z * kq2 + c[i].w * kq3;
        p += __shfl_xor(p, 1);
        p += __shfl_xor(p, 2);
        p += __shfl_xor(p, 4);
        if (q8 == 0) {
            const int n = r + i * 64;
            const float sc = p - mrow[n] * 999999999.0f;
            s_scores[n] = sc;
            lmax = fmaxf(lmax, sc);
        }
    }
    #pragma unroll
    for (int i = 0; i < LCI; ++i) {
        const float4 v = *reinterpret_cast<const float4*>(&s_data[(i * T + tid) * 4]);
        float p = v.x * kq0 + v.y * kq1 + v.z * kq2 + v.w * kq3;
        p += __shfl_xor(p, 1);
        p += __shfl_xor(p, 2);
        p += __shfl_xor(p, 4);
        if (q8 == 0) {
            const int n = r + (RCI + i) * 64;
            const float sc = p - mrow[n] * 999999999.0f;
            s_scores[n] = sc;
            lmax = fmaxf(lmax, sc);
        }
    }
    #pragma unroll
    for (int i = 0; i < GRI; ++i) {
        const float4 v = *reinterpret_cast<const float4*>(base + (RCI + LCI + i) * (64 * HH));
        float p = v.x * kq0 + v.y * kq1 + v.z * kq2 + v.w * kq3;
        p += __shfl_xor(p, 1);
        p += __shfl_xor(p, 2);
        p += __shfl_xor(p, 4);
        if (q8 == 0) {
            const int n = r + (RCI + LCI + i) * 64;
            const float sc = p - mrow[n] * 999999999.0f;
            s_scores[n] = sc;
            lmax = fmaxf(lmax, sc);
        }
    }

    // ---------------- softmax ----------------
    #pragma unroll
    for (int m = 1; m < 64; m <<= 1) lmax = fmaxf(lmax, __shfl_xor(lmax, m));
    __syncthreads();                        // all score writes done
    if ((tid & 63) == 0) red_buf[tid >> 6] = lmax;
    __syncthreads();
    float bmax = red_buf[0];
    #pragma unroll
    for (int w = 1; w < 8; ++w) bmax = fmaxf(bmax, red_buf[w]);

    float lsum = 0.f;
    #pragma unroll
    for (int k = 0; k < NN / T; ++k) {
        const int n = tid + k * T;
        const float e = expf(s_scores[n] - bmax);
        s_scores[n] = e;
        lsum += e;
    }
    #pragma unroll
    for (int m = 1; m < 64; m <<= 1) lsum += __shfl_xor(lsum, m);
    __syncthreads();                        // red_buf (max) reads done
    if ((tid & 63) == 0) red_buf[tid >> 6] = lsum;
    __syncthreads();
    float tot = red_buf[0];
    #pragma unroll
    for (int w = 1; w < 8; ++w) tot += red_buf[w];
    const float inv = 1.0f / tot;

    float* orow = out + (size_t)b * NN;
    #pragma unroll
    for (int k = 0; k < NN / T; ++k) {
        const int n = tid + k * T;
        orow[n] = s_scores[n] * inv;
    }
}

extern "C" void kernel_launch(void* const* d_in, const int* in_sizes, int n_in,
                              void* d_out, int out_size, void* d_ws, size_t ws_size,
                              hipStream_t stream) {
    (void)in_sizes; (void)n_in; (void)d_ws; (void)ws_size; (void)out_size;
    const float* ne    = (const float*)d_in[0];
    const float* mask  = (const float*)d_in[1];
    const float* times = (const float*)d_in[2];
    // d_in[3] = vf, unused (idxc path taken)
    const float* W1    = (const float*)d_in[4];
    const float* b1    = (const float*)d_in[5];
    const float* Wq    = (const float*)d_in[6];
    const float* Wk    = (const float*)d_in[7];
    const int*   idxc  = (const int*)d_in[8];
    float* out = (float*)d_out;

    gnd_kernel<<<dim3(BB), dim3(T), 0, stream>>>(
        ne, mask, times, W1, b1, Wq, Wk, idxc, out);
}

// Round 4
// 200.634 us; speedup vs baseline: 1.3371x; 1.3371x over previous
//
#include <hip/hip_runtime.h>
#include <math.h>

#define BB 1024
#define NN 4096
#define HH 32
#define PP 4                 // K1 partial blocks per batch
#define RK1 (NN / PP)        // 1024 rows per K1 block

// ws layout (floats)
#define WS_PART 0                    // [BB*PP*HH) column-sum partials
#define WS_QK   (BB * PP * HH)       // [BB*HH) folded query vectors

// ---------------- K1: per-batch column-sum partials ----------------
// grid = BB*PP blocks x 256 thr. Pure load stream, 32 waves/CU occupancy.
__global__ __launch_bounds__(256) void k1_colsum(
    const float* __restrict__ ne, float* __restrict__ ws)
{
    const int blk = blockIdx.x;
    const int b   = blk >> 2;
    const int p   = blk & (PP - 1);
    const int tid = threadIdx.x;
    const int q8  = tid & 7;     // float4 chunk within row
    const int r   = tid >> 3;    // row offset 0..31

    __shared__ float s_part[256 * 4];

    const float* base = ne + (size_t)b * (NN * HH)
                           + (size_t)(p * RK1 + r) * HH + q8 * 4;
    float a0 = 0.f, a1 = 0.f, a2 = 0.f, a3 = 0.f;
    #pragma unroll 8
    for (int i = 0; i < RK1 / 32; ++i) {               // 32 iters
        const float4 v = *reinterpret_cast<const float4*>(base + i * (32 * HH));
        a0 += v.x; a1 += v.y; a2 += v.z; a3 += v.w;
    }
    *reinterpret_cast<float4*>(&s_part[tid * 4]) = make_float4(a0, a1, a2, a3);
    __syncthreads();

    // deterministic fixed-order reduce: thread h sums its column's 32 partials
    if (tid < HH) {
        const int q = tid >> 2, j = tid & 3;
        float s = 0.f;
        #pragma unroll
        for (int rr = 0; rr < 32; ++rr) s += s_part[(rr * 8 + q) * 4 + j];
        ws[WS_PART + (b * PP + p) * HH + tid] = s;
    }
}

// ---------------- K2: per-batch tiny MLP -> qk ----------------
// grid = BB blocks x 64 thr.
__global__ __launch_bounds__(64) void k2_mlp(
    const float* __restrict__ ne, const float* __restrict__ times,
    const float* __restrict__ W1, const float* __restrict__ b1,
    const float* __restrict__ Wq, const float* __restrict__ Wk,
    const int* __restrict__ idxc, float* __restrict__ ws)
{
    const int b   = blockIdx.x;
    const int tid = threadIdx.x;
    __shared__ float sh_avg[HH], sh_f[HH], sh_emb[HH], sh_q[HH];

    if (tid < HH) {
        float s = 0.f;
        #pragma unroll
        for (int p = 0; p < PP; ++p) s += ws[WS_PART + (b * PP + p) * HH + tid];
        sh_avg[tid] = s * (1.0f / (float)NN);
        sh_f[tid]   = ne[(size_t)b * (NN * HH) + (size_t)idxc[b] * HH + tid];
    }
    __syncthreads();
    if (tid < HH) {
        const float t = times[b];
        const float* w = W1 + tid * (2 * HH + 1);
        float e = b1[tid];
        #pragma unroll
        for (int j = 0; j < HH; ++j) e += sh_avg[j] * w[j];
        #pragma unroll
        for (int j = 0; j < HH; ++j) e += sh_f[j] * w[HH + j];
        e += t * w[2 * HH];
        sh_emb[tid] = e;
    }
    __syncthreads();
    if (tid < HH) {
        const float* w = Wq + tid * HH;
        float qv = 0.f;
        #pragma unroll
        for (int j = 0; j < HH; ++j) qv += sh_emb[j] * w[j];
        sh_q[tid] = qv;
    }
    __syncthreads();
    if (tid < HH) {
        float s = 0.f;
        #pragma unroll
        for (int h = 0; h < HH; ++h) s += sh_q[h] * Wk[h * HH + tid];
        ws[WS_QK + b * HH + tid] = s * 0.17677669529663687f;   // 1/sqrt(32)
    }
}

// ---------------- K3: scores + softmax ----------------
// grid = BB blocks x 256 thr, LDS 16.5 KB -> 8 blocks/CU resident.
__global__ __launch_bounds__(256) void k3_scores(
    const float* __restrict__ ne, const float* __restrict__ mask,
    const float* __restrict__ ws, float* __restrict__ out)
{
    const int b   = blockIdx.x;
    const int tid = threadIdx.x;
    const int q8  = tid & 7;
    const int r   = tid >> 3;    // 0..31

    __shared__ float s_scores[NN];     // 16 KB
    __shared__ float sh_qk[HH];
    __shared__ float red_buf[4];

    if (tid < HH) sh_qk[tid] = ws[WS_QK + b * HH + tid];
    __syncthreads();

    const float kq0 = sh_qk[q8 * 4 + 0];
    const float kq1 = sh_qk[q8 * 4 + 1];
    const float kq2 = sh_qk[q8 * 4 + 2];
    const float kq3 = sh_qk[q8 * 4 + 3];

    const float* base = ne + (size_t)b * (NN * HH) + (size_t)r * HH + q8 * 4;

    // raw dot products into LDS (8 consecutive active lanes -> no bank conflict)
    #pragma unroll 8
    for (int i = 0; i < NN / 32; ++i) {               // 128 iters
        const float4 v = *reinterpret_cast<const float4*>(base + i * (32 * HH));
        float p = v.x * kq0 + v.y * kq1 + v.z * kq2 + v.w * kq3;
        p += __shfl_xor(p, 1);
        p += __shfl_xor(p, 2);
        p += __shfl_xor(p, 4);
        if (q8 == 0) s_scores[r + i * 32] = p;
    }
    __syncthreads();

    // apply mask (coalesced), block max
    const float* mrow = mask + (size_t)b * NN;
    float lmax = -INFINITY;
    #pragma unroll
    for (int k = 0; k < NN / 256; ++k) {
        const int n = tid + k * 256;
        const float sc = s_scores[n] - mrow[n] * 999999999.0f;
        s_scores[n] = sc;
        lmax = fmaxf(lmax, sc);
    }
    #pragma unroll
    for (int m = 1; m < 64; m <<= 1) lmax = fmaxf(lmax, __shfl_xor(lmax, m));
    if ((tid & 63) == 0) red_buf[tid >> 6] = lmax;
    __syncthreads();
    const float bmax = fmaxf(fmaxf(red_buf[0], red_buf[1]),
                             fmaxf(red_buf[2], red_buf[3]));

    // exp + sum
    float lsum = 0.f;
    #pragma unroll
    for (int k = 0; k < NN / 256; ++k) {
        const int n = tid + k * 256;
        const float e = expf(s_scores[n] - bmax);
        s_scores[n] = e;
        lsum += e;
    }
    #pragma unroll
    for (int m = 1; m < 64; m <<= 1) lsum += __shfl_xor(lsum, m);
    __syncthreads();                       // red_buf (max) reads done
    if ((tid & 63) == 0) red_buf[tid >> 6] = lsum;
    __syncthreads();
    const float inv = 1.0f / (red_buf[0] + red_buf[1] + red_buf[2] + red_buf[3]);

    float* orow = out + (size_t)b * NN;
    #pragma unroll
    for (int k = 0; k < NN / 256; ++k) {
        const int n = tid + k * 256;
        orow[n] = s_scores[n] * inv;
    }
}

extern "C" void kernel_launch(void* const* d_in, const int* in_sizes, int n_in,
                              void* d_out, int out_size, void* d_ws, size_t ws_size,
                              hipStream_t stream) {
    (void)in_sizes; (void)n_in; (void)ws_size; (void)out_size;
    const float* ne    = (const float*)d_in[0];
    const float* mask  = (const float*)d_in[1];
    const float* times = (const float*)d_in[2];
    // d_in[3] = vf, unused (idxc path taken)
    const float* W1    = (const float*)d_in[4];
    const float* b1    = (const float*)d_in[5];
    const float* Wq    = (const float*)d_in[6];
    const float* Wk    = (const float*)d_in[7];
    const int*   idxc  = (const int*)d_in[8];
    float* out = (float*)d_out;
    float* ws  = (float*)d_ws;

    k1_colsum<<<dim3(BB * PP), dim3(256), 0, stream>>>(ne, ws);
    k2_mlp<<<dim3(BB), dim3(64), 0, stream>>>(ne, times, W1, b1, Wq, Wk, idxc, ws);
    k3_scores<<<dim3(BB), dim3(256), 0, stream>>>(ne, mask, ws, out);
}